// Round 13
// baseline (20.667 us; speedup 1.0000x reference)
//
#include <hip/hip_runtime.h>
#include <math.h>

// probs/targets: (32,1,512,512) fp32
// ROUND 13: wave-collective SALU counting. Counting (cgt/cnt/gt) moves to
// ballot + s_bcnt1 (SGPR accumulators, scalar pipe): 2 VALU/elem (the cmps)
// instead of ~6+. Wave max reduced FIRST (DPP/permlane, r12-validated) so
// the eq-ballot tests against a wave-uniform mg. Butterfly: only s1/s2/dt.
// One partial set per WAVE; no LDS, no syncthreads in k_partial.
#define NS 32
#define NELEM 262144
#define TPB 256

__device__ __forceinline__ unsigned f2u(float x) { return __builtin_bit_cast(unsigned, x); }
__device__ __forceinline__ float u2f(unsigned x) { return __builtin_bit_cast(float, x); }

template<int CTRL>
__device__ __forceinline__ float dpp_mov_f(float v) {
    return u2f((unsigned)__builtin_amdgcn_update_dpp((int)f2u(v), (int)f2u(v),
                                                     CTRL, 0xF, 0xF, false));
}

#if __has_builtin(__builtin_amdgcn_permlane16_swap) && __has_builtin(__builtin_amdgcn_permlane32_swap)
#define HAVE_PERMLANE_SWAP 1
#else
#define HAVE_PERMLANE_SWAP 0
#endif

// full 64-lane max, result uniform across the wave (rotate-reduce + swaps)
__device__ __forceinline__ float wave_max(float v) {
    v = fmaxf(v, dpp_mov_f<0x128>(v));   // row_ror:8
    v = fmaxf(v, dpp_mov_f<0x124>(v));   // row_ror:4
    v = fmaxf(v, dpp_mov_f<0x122>(v));   // row_ror:2
    v = fmaxf(v, dpp_mov_f<0x121>(v));   // row_ror:1
#if HAVE_PERMLANE_SWAP
    { auto r = __builtin_amdgcn_permlane16_swap(f2u(v), f2u(v), false, false);
      v = fmaxf(u2f(r[0]), u2f(r[1])); }
    { auto r = __builtin_amdgcn_permlane32_swap(f2u(v), f2u(v), false, false);
      v = fmaxf(u2f(r[0]), u2f(r[1])); }
#else
    v = fmaxf(v, __shfl_xor(v, 16));
    v = fmaxf(v, __shfl_xor(v, 32));
#endif
    return v;
}

__device__ __forceinline__ float wave_sum(float v) {
    v += dpp_mov_f<0x128>(v);
    v += dpp_mov_f<0x124>(v);
    v += dpp_mov_f<0x122>(v);
    v += dpp_mov_f<0x121>(v);
#if HAVE_PERMLANE_SWAP
    { auto r = __builtin_amdgcn_permlane16_swap(f2u(v), f2u(v), false, false);
      v = u2f(r[0]) + u2f(r[1]); }
    { auto r = __builtin_amdgcn_permlane32_swap(f2u(v), f2u(v), false, false);
      v = u2f(r[0]) + u2f(r[1]); }
#else
    v += __shfl_xor(v, 16);
    v += __shfl_xor(v, 32);
#endif
    return v;
}

// PASSES x 16 elem/thread; ONE partial set per wave; counts in SGPRs.
// ws layout (nsets = gridDim*4): s1|s2|dot|mx floats, then cgt|pk ints.
template<int PASSES, int MINW>
__global__ __launch_bounds__(TPB, MINW) void k_partial(const float* __restrict__ probs,
                                                       const float* __restrict__ tgts,
                                                       float* __restrict__ wsf,
                                                       int* __restrict__ wsi,
                                                       int nsets) {
    constexpr int EPB = PASSES * TPB * 16;   // elements per block
    constexpr int BPS = NELEM / EPB;         // blocks per sample
    const int b = blockIdx.x;
    const int s = b / BPS;
    const int c = b % BPS;
    const size_t base = (size_t)s * NELEM + (size_t)c * EPB;
    const float4* __restrict__ p4 = (const float4*)(probs + base);
    const float4* __restrict__ t4 = (const float4*)(tgts + base);
    const int t = threadIdx.x;

    float4 a1 = {0.f,0.f,0.f,0.f}, a2 = {0.f,0.f,0.f,0.f}, ad = {0.f,0.f,0.f,0.f};
    float mx_run = -INFINITY;
    int cgt_run = 0, cnt_run = 0, gt_run = 0;   // wave-uniform (SGPR)

#pragma unroll
    for (int g = 0; g < PASSES; ++g) {
        float4 pv[4], tv[4];
#pragma unroll
        for (int k = 0; k < 4; ++k) {
            pv[k] = p4[g * 1024 + k * 256 + t];
            tv[k] = t4[g * 1024 + k * 256 + t];
        }

        // sums — component-parallel
#pragma unroll
        for (int k = 0; k < 4; ++k) {
            a1.x += pv[k].x; a1.y += pv[k].y; a1.z += pv[k].z; a1.w += pv[k].w;
            a2.x += tv[k].x; a2.y += tv[k].y; a2.z += tv[k].z; a2.w += tv[k].w;
            ad.x = fmaf(pv[k].x, tv[k].x, ad.x);
            ad.y = fmaf(pv[k].y, tv[k].y, ad.y);
            ad.z = fmaf(pv[k].z, tv[k].z, ad.z);
            ad.w = fmaf(pv[k].w, tv[k].w, ad.w);
        }

        // thread max (pairwise tree) then wave-uniform max
        const float mX = fmaxf(fmaxf(tv[0].x, tv[1].x), fmaxf(tv[2].x, tv[3].x));
        const float mY = fmaxf(fmaxf(tv[0].y, tv[1].y), fmaxf(tv[2].y, tv[3].y));
        const float mZ = fmaxf(fmaxf(tv[0].z, tv[1].z), fmaxf(tv[2].z, tv[3].z));
        const float mW = fmaxf(fmaxf(tv[0].w, tv[1].w), fmaxf(tv[2].w, tv[3].w));
        const float mg = wave_max(fmaxf(fmaxf(mX, mY), fmaxf(mZ, mW)));

        // counting: 2 v_cmp per element; accumulate on the scalar pipe
        int cgt_p = 0, cnt_p = 0, gt_p = 0;
#define CNT1(P, T) { const unsigned long long bm = __ballot((P) > 0.5f); \
                     const unsigned long long em = __ballot((T) == mg);  \
                     cgt_p += (int)__popcll(bm);                         \
                     cnt_p += (int)__popcll(em);                         \
                     gt_p  += (int)__popcll(em & bm); }
#pragma unroll
        for (int k = 0; k < 4; ++k) {
            CNT1(pv[k].x, tv[k].x);
            CNT1(pv[k].y, tv[k].y);
            CNT1(pv[k].z, tv[k].z);
            CNT1(pv[k].w, tv[k].w);
        }
#undef CNT1

        // merge pass results (wave-uniform scalar semigroup)
        if (g == 0) {
            mx_run = mg; cnt_run = cnt_p; gt_run = gt_p; cgt_run = cgt_p;
        } else {
            const bool gr = mg > mx_run;
            const bool eq = mg == mx_run;
            cnt_run = gr ? cnt_p : (cnt_run + (eq ? cnt_p : 0));
            gt_run  = gr ? gt_p  : (gt_run  + (eq ? gt_p  : 0));
            mx_run = fmaxf(mx_run, mg);
            cgt_run += cgt_p;
        }
    }

    // wave-reduce the three float sums (DPP/permlane, VALU pipe)
    const float s1 = wave_sum((a1.x + a1.y) + (a1.z + a1.w));
    const float s2 = wave_sum((a2.x + a2.y) + (a2.z + a2.w));
    const float dt = wave_sum((ad.x + ad.y) + (ad.z + ad.w));

    if ((t & 63) == 0) {
        const int g = b * (TPB / 64) + (t >> 6);    // one set per wave
        wsf[0 * nsets + g] = s1;
        wsf[1 * nsets + g] = s2;
        wsf[2 * nsets + g] = dt;
        wsf[3 * nsets + g] = mx_run;
        wsi[4 * nsets + g] = cgt_run;
        wsi[5 * nsets + g] = (cnt_run << 16) | gt_run;  // wave counts <= 4096
    }
}

__device__ __forceinline__ void combine_max(float& mx, int& cnt, int& gt,
                                            float mx2, int cnt2, int gt2) {
    if (mx2 > mx) { mx = mx2; cnt = cnt2; gt = gt2; }
    else if (mx2 == mx) { cnt += cnt2; gt += gt2; }
}

// one block per sample; SPS sets/sample, one per thread; unpack pk before
// reducing (sample-level counts exceed 16 bits)
template<int SPS>
__global__ __launch_bounds__(SPS) void k_sample(const float* __restrict__ wsf,
                                                const int* __restrict__ wsi,
                                                float* __restrict__ scores,
                                                int nsets) {
    const int s = blockIdx.x;
    const int t = threadIdx.x;
    const int idx = s * SPS + t;

    float s1 = wsf[0 * nsets + idx];
    float s2 = wsf[1 * nsets + idx];
    float dt = wsf[2 * nsets + idx];
    float mx = wsf[3 * nsets + idx];
    int  cgt = wsi[4 * nsets + idx];
    const int pk = wsi[5 * nsets + idx];
    int cnt = pk >> 16;
    int gt  = pk & 0xFFFF;

#pragma unroll
    for (int off = 32; off; off >>= 1) {
        s1  += __shfl_xor(s1, off);
        s2  += __shfl_xor(s2, off);
        dt  += __shfl_xor(dt, off);
        cgt += __shfl_xor(cgt, off);
        float m2 = __shfl_xor(mx, off);
        int   c2 = __shfl_xor(cnt, off);
        int   g2 = __shfl_xor(gt, off);
        combine_max(mx, cnt, gt, m2, c2, g2);
    }

    if constexpr (SPS > 64) {
        __shared__ float ls1[SPS / 64], ls2[SPS / 64], ldt[SPS / 64], lmx[SPS / 64];
        __shared__ int   lcg[SPS / 64], lcn[SPS / 64], lgt[SPS / 64];
        const int w = t >> 6;
        if ((t & 63) == 0) {
            ls1[w] = s1; ls2[w] = s2; ldt[w] = dt; lmx[w] = mx;
            lcg[w] = cgt; lcn[w] = cnt; lgt[w] = gt;
        }
        __syncthreads();
        if (t == 0) {
#pragma unroll
            for (int w2 = 1; w2 < SPS / 64; ++w2) {
                s1 += ls1[w2]; s2 += ls2[w2]; dt += ldt[w2]; cgt += lcg[w2];
                combine_max(mx, cnt, gt, lmx[w2], lcn[w2], lgt[w2]);
            }
        }
    }

    if (t == 0) {
        const int cle = NELEM - cgt;   // count(p <= 0.5)
        const long long corr = (long long)cle - (long long)cnt + 2LL * (long long)gt;
        float score = 2.0f * (dt + 1.0f) / (s1 + s2 + 1.0f);
        if (corr == 1) score = 1.0f;   // acc == 1.0 (probs.shape[1] == 1)
        scores[s] = 1.0f - score;
    }
}

__global__ __launch_bounds__(64) void k_mean(const float* __restrict__ scores,
                                             float* __restrict__ out) {
    const int t = threadIdx.x;
    float v = (t < NS) ? scores[t] : 0.0f;
#pragma unroll
    for (int off = 32; off; off >>= 1) v += __shfl_xor(v, off);
    if (t == 0) out[0] = v * (1.0f / (float)NS);
}

extern "C" void kernel_launch(void* const* d_in, const int* in_sizes, int n_in,
                              void* d_out, int out_size, void* d_ws, size_t ws_size,
                              hipStream_t stream) {
    const float* probs = (const float*)d_in[0];
    const float* tgts  = (const float*)d_in[1];
    float* wsf = (float*)d_ws;
    int*   wsi = (int*)d_ws;
    float* out = (float*)d_out;

    const size_t need_big = (size_t)(6 * 8192 + NS) * sizeof(float);
    if (ws_size >= need_big) {
        // 2048 blocks x 16 elem/thread, full occupancy (probe-proven 13.7 TB/s)
        const int nsets = 8192;
        k_partial<1, 8><<<2048, TPB, 0, stream>>>(probs, tgts, wsf, wsi, nsets);
        k_sample<256><<<NS, 256, 0, stream>>>(wsf, wsi, wsf + 6 * nsets, nsets);
        k_mean<<<1, 64, 0, stream>>>(wsf + 6 * nsets, out);
    } else {
        // fallback: 512 blocks x 4 passes (49 KB ws)
        const int nsets = 2048;
        k_partial<4, 4><<<512, TPB, 0, stream>>>(probs, tgts, wsf, wsi, nsets);
        k_sample<64><<<NS, 64, 0, stream>>>(wsf, wsi, wsf + 6 * nsets, nsets);
        k_mean<<<1, 64, 0, stream>>>(wsf + 6 * nsets, out);
    }
}